// Round 1
// baseline (2877.657 us; speedup 1.0000x reference)
//
#include <hip/hip_runtime.h>
#include <hip/hip_bf16.h>

#define BB 64
#define CC 512
#define NN 1024
#define CQ 64

typedef __hip_bfloat16 bf16;

// ---------------------------------------------------------------------------
// K1: Y[b] = [Wq; Wk; Wv] (640x512) @ x[b] (512x1024)
// rows 0..63 -> f (fp32), 64..127 -> g (fp32), 128..639 -> h (bf16)
// ---------------------------------------------------------------------------
__global__ __launch_bounds__(256) void fgh_kernel(
    const float* __restrict__ x, const float* __restrict__ Wq,
    const float* __restrict__ Wk, const float* __restrict__ Wv,
    float* __restrict__ fo, float* __restrict__ go, bf16* __restrict__ ho)
{
    __shared__ float Wt[64][33];
    __shared__ float xt[32][64];
    const int t  = threadIdx.x;
    const int b  = blockIdx.z;
    const int n0 = blockIdx.x * 64;
    const int r0 = blockIdx.y * 64;
    const int tr = t >> 4, tc = t & 15;
    float acc[4][4] = {};

    for (int k0 = 0; k0 < CC; k0 += 32) {
        {
            const int row = t >> 5;   // 0..7
            const int col = t & 31;
            #pragma unroll
            for (int it = 0; it < 8; ++it) {
                const int r = r0 + it * 8 + row;
                const float* wr;
                if (r < CQ)          wr = Wq + (size_t)r * CC;
                else if (r < 2 * CQ) wr = Wk + (size_t)(r - CQ) * CC;
                else                 wr = Wv + (size_t)(r - 2 * CQ) * CC;
                Wt[it * 8 + row][col] = wr[k0 + col];
            }
            const int k = t >> 6;     // 0..3
            const int n = t & 63;
            #pragma unroll
            for (int it = 0; it < 8; ++it) {
                xt[it * 4 + k][n] =
                    x[((size_t)b * CC + (k0 + it * 4 + k)) * NN + n0 + n];
            }
        }
        __syncthreads();
        #pragma unroll
        for (int kk = 0; kk < 32; ++kk) {
            float av[4], bv[4];
            #pragma unroll
            for (int i = 0; i < 4; ++i) av[i] = Wt[tr * 4 + i][kk];
            #pragma unroll
            for (int j = 0; j < 4; ++j) bv[j] = xt[kk][tc * 4 + j];
            #pragma unroll
            for (int i = 0; i < 4; ++i)
                #pragma unroll
                for (int j = 0; j < 4; ++j)
                    acc[i][j] += av[i] * bv[j];
        }
        __syncthreads();
    }

    if (r0 == 0) {
        #pragma unroll
        for (int i = 0; i < 4; ++i)
            #pragma unroll
            for (int j = 0; j < 4; ++j)
                fo[((size_t)b * CQ + tr * 4 + i) * NN + n0 + tc * 4 + j] = acc[i][j];
    } else if (r0 == 64) {
        #pragma unroll
        for (int i = 0; i < 4; ++i)
            #pragma unroll
            for (int j = 0; j < 4; ++j)
                go[((size_t)b * CQ + tr * 4 + i) * NN + n0 + tc * 4 + j] = acc[i][j];
    } else {
        const int rh = r0 - 128;
        #pragma unroll
        for (int i = 0; i < 4; ++i)
            #pragma unroll
            for (int j = 0; j < 4; ++j)
                ho[((size_t)b * CC + rh + tr * 4 + i) * NN + n0 + tc * 4 + j] =
                    __float2bfloat16(acc[i][j]);
    }
}

// ---------------------------------------------------------------------------
// K2: ST[m,n] = sum_q g[b,q,m]*f[b,q,n]; leaky_relu; row softmax over n;
//     beta = e*mask / (sum(e*mask) + EPS*Z); store betaT[b,m,n] as bf16.
// Block: 256 thr, m-tile = 8.  Wave w computes all 8 m over n in
// [w*256,(w+1)*256) into LDS; then wave w reduces rows w*2, w*2+1 over full n.
// ---------------------------------------------------------------------------
__global__ __launch_bounds__(256) void softmax_kernel(
    const float* __restrict__ f, const float* __restrict__ g,
    const float* __restrict__ mask, bf16* __restrict__ btT)
{
    __shared__ float stl[8][1024];
    const int t = threadIdx.x, lane = t & 63, w = t >> 6;
    const int b = blockIdx.y, m0 = blockIdx.x * 8;

    float gv[8];
    #pragma unroll
    for (int mi = 0; mi < 8; ++mi)
        gv[mi] = g[((size_t)b * CQ + lane) * NN + m0 + mi];   // lane holds q=lane

    float st[4][8];
    #pragma unroll
    for (int a = 0; a < 4; ++a)
        #pragma unroll
        for (int c2 = 0; c2 < 8; ++c2) st[a][c2] = 0.f;

    #pragma unroll
    for (int ktl = 0; ktl < 4; ++ktl) {
        const float* fp = f + (size_t)b * CQ * NN + w * 256 + ktl * 64 + lane;
        #pragma unroll 8
        for (int q = 0; q < 64; ++q) {
            const float fv = fp[(size_t)q * NN];
            #pragma unroll
            for (int mi = 0; mi < 8; ++mi)
                st[ktl][mi] += fv * __shfl(gv[mi], q);
        }
    }
    #pragma unroll
    for (int ktl = 0; ktl < 4; ++ktl)
        #pragma unroll
        for (int mi = 0; mi < 8; ++mi)
            stl[mi][w * 256 + ktl * 64 + lane] = st[ktl][mi];
    __syncthreads();

    float mk[16];
    #pragma unroll
    for (int kt = 0; kt < 16; ++kt)
        mk[kt] = mask[(size_t)b * NN + kt * 64 + lane];

    #pragma unroll
    for (int mi = 0; mi < 2; ++mi) {
        const int mrow = w * 2 + mi;
        float M = -3.4e38f;
        #pragma unroll
        for (int kt = 0; kt < 16; ++kt) {
            float s = stl[mrow][kt * 64 + lane];
            s = s >= 0.f ? s : 0.2f * s;
            M = fmaxf(M, s);
        }
        #pragma unroll
        for (int off = 32; off > 0; off >>= 1)
            M = fmaxf(M, __shfl_xor(M, off));

        float Zp = 0.f, emp = 0.f;
        float e[16];
        #pragma unroll
        for (int kt = 0; kt < 16; ++kt) {
            float s = stl[mrow][kt * 64 + lane];
            s = s >= 0.f ? s : 0.2f * s;
            const float ev = expf(s - M);
            e[kt] = ev;
            Zp += ev;
            emp += ev * mk[kt];
        }
        #pragma unroll
        for (int off = 32; off > 0; off >>= 1) {
            Zp += __shfl_xor(Zp, off);
            emp += __shfl_xor(emp, off);
        }
        const float inv = 1.0f / (emp + 1e-6f * Zp);
        bf16* outp = btT + (size_t)b * NN * NN + (size_t)(m0 + mrow) * NN + lane;
        #pragma unroll
        for (int kt = 0; kt < 16; ++kt)
            outp[kt * 64] = __float2bfloat16(e[kt] * mk[kt] * inv);
    }
}

// ---------------------------------------------------------------------------
// K3: O[b,c,m] = gamma * (sum_n h[b,c,n]*betaT[b,m,n]) * mask[b,m] + x[b,c,m]
// ---------------------------------------------------------------------------
__global__ __launch_bounds__(256) void pv_kernel(
    const bf16* __restrict__ h, const bf16* __restrict__ btT,
    const float* __restrict__ mask, const float* __restrict__ x,
    const float* __restrict__ gamma, float* __restrict__ out)
{
    __shared__ float ht[64][33];
    __shared__ float bt[64][33];
    const int t  = threadIdx.x;
    const int b  = blockIdx.z;
    const int m0 = blockIdx.x * 64;
    const int c0 = blockIdx.y * 64;
    const int tr = t >> 4, tc = t & 15;
    float acc[4][4] = {};

    for (int k0 = 0; k0 < NN; k0 += 32) {
        const int row = t >> 5, col = t & 31;
        #pragma unroll
        for (int it = 0; it < 8; ++it) {
            ht[it * 8 + row][col] = __bfloat162float(
                h[((size_t)b * CC + c0 + it * 8 + row) * NN + k0 + col]);
            bt[it * 8 + row][col] = __bfloat162float(
                btT[(size_t)b * NN * NN + (size_t)(m0 + it * 8 + row) * NN + k0 + col]);
        }
        __syncthreads();
        #pragma unroll
        for (int kk = 0; kk < 32; ++kk) {
            float av[4], bv[4];
            #pragma unroll
            for (int i = 0; i < 4; ++i) av[i] = ht[tr * 4 + i][kk];
            #pragma unroll
            for (int j = 0; j < 4; ++j) bv[j] = bt[tc * 4 + j][kk];
            #pragma unroll
            for (int i = 0; i < 4; ++i)
                #pragma unroll
                for (int j = 0; j < 4; ++j)
                    acc[i][j] += av[i] * bv[j];
        }
        __syncthreads();
    }

    const float gm = gamma[0];
    #pragma unroll
    for (int i = 0; i < 4; ++i) {
        const int c = c0 + tr * 4 + i;
        const size_t base = ((size_t)b * CC + c) * NN;
        #pragma unroll
        for (int j = 0; j < 4; ++j) {
            const int m = m0 + tc * 4 + j;
            out[base + m] = gm * acc[i][j] * mask[(size_t)b * NN + m] + x[base + m];
        }
    }
}

extern "C" void kernel_launch(void* const* d_in, const int* in_sizes, int n_in,
                              void* d_out, int out_size, void* d_ws, size_t ws_size,
                              hipStream_t stream)
{
    const float* x     = (const float*)d_in[0];
    const float* mask  = (const float*)d_in[1];
    const float* Wq    = (const float*)d_in[2];
    const float* Wk    = (const float*)d_in[3];
    const float* Wv    = (const float*)d_in[4];
    const float* gamma = (const float*)d_in[5];
    float* out = (float*)d_out;

    // workspace layout (total ~235 MB):
    //   f    fp32 [B][CQ][N]   16.8 MB
    //   g    fp32 [B][CQ][N]   16.8 MB
    //   h    bf16 [B][C][N]    67.1 MB
    //   btT  bf16 [B][N][N]   134.2 MB  (betaT[b][m][n] = beta[b][n][m])
    float* f  = (float*)d_ws;
    float* g  = f + (size_t)BB * CQ * NN;
    bf16*  h  = (bf16*)(g + (size_t)BB * CQ * NN);
    bf16*  bt = h + (size_t)BB * CC * NN;

    dim3 g1(NN / 64, 640 / 64, BB);
    fgh_kernel<<<g1, 256, 0, stream>>>(x, Wq, Wk, Wv, f, g, h);

    dim3 g2(NN / 8, BB);
    softmax_kernel<<<g2, 256, 0, stream>>>(f, g, mask, bt);

    dim3 g3(NN / 64, CC / 64, BB);
    pv_kernel<<<g3, 256, 0, stream>>>(h, bt, mask, x, gamma, out);
}

// Round 2
// 636.899 us; speedup vs baseline: 4.5182x; 4.5182x over previous
//
#include <hip/hip_runtime.h>
#include <hip/hip_bf16.h>

#define BB 64
#define CC 512
#define NN 1024
#define CQ 64

typedef unsigned short ushort_t;
typedef __attribute__((ext_vector_type(8))) short short8;
typedef __attribute__((ext_vector_type(4))) float f32x4;

__device__ __forceinline__ ushort_t f2bf(float v) {
    __hip_bfloat16 h = __float2bfloat16(v);
    return *(ushort_t*)&h;
}
__device__ __forceinline__ float bf2f(ushort_t u) {
    __hip_bfloat16 h;
    *(ushort_t*)&h = u;
    return __bfloat162float(h);
}
__device__ __forceinline__ void async_cp16(const void* g, void* l) {
    __builtin_amdgcn_global_load_lds(
        (const __attribute__((address_space(1))) unsigned int*)g,
        (__attribute__((address_space(3))) unsigned int*)l, 16, 0, 0);
}

// ---------------------------------------------------------------------------
// prep_w: split [Wq;Wk;Wv] (640x512 fp32) into whi bf16 (640 rows) and
// wlo bf16 (first 128 rows only).
// ---------------------------------------------------------------------------
__global__ __launch_bounds__(256) void prep_w(
    const float* __restrict__ Wq, const float* __restrict__ Wk,
    const float* __restrict__ Wv, ushort_t* __restrict__ whi,
    ushort_t* __restrict__ wlo)
{
    const int i = blockIdx.x * 256 + threadIdx.x;  // over 640*512
    if (i >= 640 * 512) return;
    float v;
    if (i < 32768)      v = Wq[i];
    else if (i < 65536) v = Wk[i - 32768];
    else                v = Wv[i - 65536];
    const ushort_t hu = f2bf(v);
    whi[i] = hu;
    if (i < 65536) wlo[i] = f2bf(v - bf2f(hu));
}

// ---------------------------------------------------------------------------
// xtrans: x[b][c][n] fp32 -> xthi/xtlo[b][n][c] bf16 (64x64 LDS tile transpose)
// ---------------------------------------------------------------------------
__global__ __launch_bounds__(256) void xtrans(
    const float* __restrict__ x, ushort_t* __restrict__ xthi,
    ushort_t* __restrict__ xtlo)
{
    __shared__ float ld[64][65];
    const int t = threadIdx.x;
    const int b = blockIdx.z, cb = blockIdx.y * 64, n0 = blockIdx.x * 64;

    #pragma unroll
    for (int p = 0; p < 4; ++p) {
        const int c = (t >> 4) + 16 * p;
        const float4 v = *(const float4*)&x[((size_t)b * CC + cb + c) * NN + n0 + (t & 15) * 4];
        ld[c][(t & 15) * 4 + 0] = v.x;
        ld[c][(t & 15) * 4 + 1] = v.y;
        ld[c][(t & 15) * 4 + 2] = v.z;
        ld[c][(t & 15) * 4 + 3] = v.w;
    }
    __syncthreads();

    #pragma unroll
    for (int p = 0; p < 2; ++p) {
        const int nr = (t >> 3) + 32 * p;
        ushort_t hs[8], ls[8];
        #pragma unroll
        for (int j = 0; j < 8; ++j) {
            const float v = ld[(t & 7) * 8 + j][nr];
            const ushort_t hu = f2bf(v);
            hs[j] = hu;
            ls[j] = f2bf(v - bf2f(hu));
        }
        uint4 H, L;
        H.x = hs[0] | ((unsigned)hs[1] << 16); H.y = hs[2] | ((unsigned)hs[3] << 16);
        H.z = hs[4] | ((unsigned)hs[5] << 16); H.w = hs[6] | ((unsigned)hs[7] << 16);
        L.x = ls[0] | ((unsigned)ls[1] << 16); L.y = ls[2] | ((unsigned)ls[3] << 16);
        L.z = ls[4] | ((unsigned)ls[5] << 16); L.w = ls[6] | ((unsigned)ls[7] << 16);
        const size_t idx = ((size_t)b * NN + n0 + nr) * CC + cb + (t & 7) * 8;
        *(uint4*)&xthi[idx] = H;
        *(uint4*)&xtlo[idx] = L;
    }
}

// ---------------------------------------------------------------------------
// fgh: Y = W(640x512) @ x(512x1024) per batch via MFMA.
//  m-tiles 0,1 (f,g): 3-term hi/lo split, write transposed fT/gT hi/lo bf16
//  m-tiles 2..9 (h): 1-term, write h[b][c][n] bf16
// ---------------------------------------------------------------------------
__global__ __launch_bounds__(256) void fgh_kernel(
    const ushort_t* __restrict__ whi, const ushort_t* __restrict__ wlo,
    const ushort_t* __restrict__ xthi, const ushort_t* __restrict__ xtlo,
    ushort_t* __restrict__ fgout, ushort_t* __restrict__ h)
{
    __shared__ __align__(16) ushort_t sWhi[64 * 64], sWlo[64 * 64];
    __shared__ __align__(16) ushort_t sXhi[64 * 64], sXlo[64 * 64];
    const int t = threadIdx.x, l = t & 63, w = t >> 6;
    const int b = blockIdx.z, n0 = blockIdx.x * 64, my = blockIdx.y, m0 = my * 64;
    const bool fg = (my < 2);
    const int wr = w >> 1, wc = w & 1;
    f32x4 acc[2][2] = {};

    const int e0 = t * 8, e1 = (256 + t) * 8;
    const int r0 = e0 >> 6, c0v = e0 & 63, r1 = e1 >> 6, c1v = e1 & 63;

    for (int kt = 0; kt < 8; ++kt) {
        const int k0 = kt * 64;
        async_cp16(whi + (size_t)(m0 + r0) * CC + k0 + c0v, (char*)sWhi + t * 16);
        async_cp16(whi + (size_t)(m0 + r1) * CC + k0 + c1v, (char*)sWhi + 4096 + t * 16);
        async_cp16(xthi + ((size_t)b * NN + n0 + r0) * CC + k0 + c0v, (char*)sXhi + t * 16);
        async_cp16(xthi + ((size_t)b * NN + n0 + r1) * CC + k0 + c1v, (char*)sXhi + 4096 + t * 16);
        if (fg) {
            async_cp16(wlo + (size_t)(m0 + r0) * CC + k0 + c0v, (char*)sWlo + t * 16);
            async_cp16(wlo + (size_t)(m0 + r1) * CC + k0 + c1v, (char*)sWlo + 4096 + t * 16);
            async_cp16(xtlo + ((size_t)b * NN + n0 + r0) * CC + k0 + c0v, (char*)sXlo + t * 16);
            async_cp16(xtlo + ((size_t)b * NN + n0 + r1) * CC + k0 + c1v, (char*)sXlo + 4096 + t * 16);
        }
        __syncthreads();
        #pragma unroll
        for (int kc = 0; kc < 2; ++kc) {
            const int fo = kc * 32 + (l >> 4) * 8;
            short8 ah[2], bh[2];
            ah[0] = *(const short8*)&sWhi[(wr * 32 + (l & 15)) * 64 + fo];
            ah[1] = *(const short8*)&sWhi[(wr * 32 + 16 + (l & 15)) * 64 + fo];
            bh[0] = *(const short8*)&sXhi[(wc * 32 + (l & 15)) * 64 + fo];
            bh[1] = *(const short8*)&sXhi[(wc * 32 + 16 + (l & 15)) * 64 + fo];
            #pragma unroll
            for (int i = 0; i < 2; ++i)
                #pragma unroll
                for (int j = 0; j < 2; ++j)
                    acc[i][j] = __builtin_amdgcn_mfma_f32_16x16x32_bf16(ah[i], bh[j], acc[i][j], 0, 0, 0);
            if (fg) {
                short8 al[2], bl[2];
                al[0] = *(const short8*)&sWlo[(wr * 32 + (l & 15)) * 64 + fo];
                al[1] = *(const short8*)&sWlo[(wr * 32 + 16 + (l & 15)) * 64 + fo];
                bl[0] = *(const short8*)&sXlo[(wc * 32 + (l & 15)) * 64 + fo];
                bl[1] = *(const short8*)&sXlo[(wc * 32 + 16 + (l & 15)) * 64 + fo];
                #pragma unroll
                for (int i = 0; i < 2; ++i)
                    #pragma unroll
                    for (int j = 0; j < 2; ++j) {
                        acc[i][j] = __builtin_amdgcn_mfma_f32_16x16x32_bf16(ah[i], bl[j], acc[i][j], 0, 0, 0);
                        acc[i][j] = __builtin_amdgcn_mfma_f32_16x16x32_bf16(al[i], bh[j], acc[i][j], 0, 0, 0);
                    }
            }
        }
        __syncthreads();
    }

    if (fg) {
        // plane layout in fgout: [fThi | fTlo | gThi | gTlo], each 64*1024*64 elems
        ushort_t* pThi = fgout + (size_t)my * 8388608;
        ushort_t* pTlo = pThi + 4194304;
        #pragma unroll
        for (int i = 0; i < 2; ++i) {
            const int qb = wr * 32 + i * 16 + (l >> 4) * 4;
            #pragma unroll
            for (int j = 0; j < 2; ++j) {
                const int n = n0 + wc * 32 + j * 16 + (l & 15);
                ushort_t hs[4], ls[4];
                #pragma unroll
                for (int r = 0; r < 4; ++r) {
                    const float v = acc[i][j][r];
                    const ushort_t hu = f2bf(v);
                    hs[r] = hu;
                    ls[r] = f2bf(v - bf2f(hu));
                }
                uint2 H, L;
                H.x = hs[0] | ((unsigned)hs[1] << 16); H.y = hs[2] | ((unsigned)hs[3] << 16);
                L.x = ls[0] | ((unsigned)ls[1] << 16); L.y = ls[2] | ((unsigned)ls[3] << 16);
                const size_t base = ((size_t)b * NN + n) * CQ + qb;
                *(uint2*)&pThi[base] = H;
                *(uint2*)&pTlo[base] = L;
            }
        }
    } else {
        const int cb = (my - 2) * 64 + wr * 32;
        #pragma unroll
        for (int i = 0; i < 2; ++i)
            #pragma unroll
            for (int j = 0; j < 2; ++j) {
                const int n = n0 + wc * 32 + j * 16 + (l & 15);
                #pragma unroll
                for (int r = 0; r < 4; ++r) {
                    const int c = cb + i * 16 + (l >> 4) * 4 + r;
                    h[((size_t)b * CC + c) * NN + n] = f2bf(acc[i][j][r]);
                }
            }
    }
}

// ---------------------------------------------------------------------------
// scores: ST[m][n] = sum_q gT[m][q]*fT[n][q] (3-term hi/lo), leaky_relu,
// row softmax over n, mask renorm, write btT[b][m][n] bf16.
// Block: 16 m-rows x full N=1024. Wave w covers n in [w*256,(w+1)*256).
// Operands read straight from L2 (no LDS staging).
// ---------------------------------------------------------------------------
__global__ __launch_bounds__(256) void scores_kernel(
    const ushort_t* __restrict__ fgout, const float* __restrict__ mask,
    ushort_t* __restrict__ btT)
{
    const ushort_t* fThi = fgout;
    const ushort_t* fTlo = fgout + 4194304;
    const ushort_t* gThi = fgout + 8388608;
    const ushort_t* gTlo = fgout + 12582912;
    __shared__ float redm[4][16], redz[4][16], rede[4][16];
    const int t = threadIdx.x, l = t & 63, w = t >> 6;
    const int m0 = blockIdx.x * 16, b = blockIdx.y;

    short8 ah[2], al[2];
    #pragma unroll
    for (int kc = 0; kc < 2; ++kc) {
        const size_t off = ((size_t)b * NN + m0 + (l & 15)) * CQ + kc * 32 + (l >> 4) * 8;
        ah[kc] = *(const short8*)&gThi[off];
        al[kc] = *(const short8*)&gTlo[off];
    }
    float mk[16];
    #pragma unroll
    for (int st = 0; st < 16; ++st)
        mk[st] = mask[(size_t)b * NN + w * 256 + st * 16 + (l & 15)];

    f32x4 acc[16] = {};
    #pragma unroll
    for (int st = 0; st < 16; ++st) {
        const size_t nb = (size_t)b * NN + w * 256 + st * 16 + (l & 15);
        #pragma unroll
        for (int kc = 0; kc < 2; ++kc) {
            const size_t off = nb * CQ + kc * 32 + (l >> 4) * 8;
            const short8 bh = *(const short8*)&fThi[off];
            const short8 bl = *(const short8*)&fTlo[off];
            acc[st] = __builtin_amdgcn_mfma_f32_16x16x32_bf16(ah[kc], bh, acc[st], 0, 0, 0);
            acc[st] = __builtin_amdgcn_mfma_f32_16x16x32_bf16(ah[kc], bl, acc[st], 0, 0, 0);
            acc[st] = __builtin_amdgcn_mfma_f32_16x16x32_bf16(al[kc], bh, acc[st], 0, 0, 0);
        }
    }
    // leaky relu
    #pragma unroll
    for (int st = 0; st < 16; ++st)
        #pragma unroll
        for (int r = 0; r < 4; ++r) {
            const float s = acc[st][r];
            acc[st][r] = s >= 0.f ? s : 0.2f * s;
        }
    // row max (rows live at (l>>4)*4+r across 16 cols = lanes l&15)
    float M[4] = {-3.4e38f, -3.4e38f, -3.4e38f, -3.4e38f};
    #pragma unroll
    for (int st = 0; st < 16; ++st)
        #pragma unroll
        for (int r = 0; r < 4; ++r) M[r] = fmaxf(M[r], acc[st][r]);
    #pragma unroll
    for (int off = 1; off <= 8; off <<= 1)
        #pragma unroll
        for (int r = 0; r < 4; ++r) M[r] = fmaxf(M[r], __shfl_xor(M[r], off));
    if ((l & 15) == 0)
        #pragma unroll
        for (int r = 0; r < 4; ++r) redm[w][(l >> 4) * 4 + r] = M[r];
    __syncthreads();
    #pragma unroll
    for (int r = 0; r < 4; ++r) {
        const int row = (l >> 4) * 4 + r;
        M[r] = fmaxf(fmaxf(redm[0][row], redm[1][row]), fmaxf(redm[2][row], redm[3][row]));
    }
    float Z[4] = {}, E[4] = {};
    #pragma unroll
    for (int st = 0; st < 16; ++st)
        #pragma unroll
        for (int r = 0; r < 4; ++r) {
            const float e = __expf(acc[st][r] - M[r]);
            Z[r] += e;
            E[r] += e * mk[st];
        }
    #pragma unroll
    for (int off = 1; off <= 8; off <<= 1)
        #pragma unroll
        for (int r = 0; r < 4; ++r) {
            Z[r] += __shfl_xor(Z[r], off);
            E[r] += __shfl_xor(E[r], off);
        }
    if ((l & 15) == 0)
        #pragma unroll
        for (int r = 0; r < 4; ++r) {
            redz[w][(l >> 4) * 4 + r] = Z[r];
            rede[w][(l >> 4) * 4 + r] = E[r];
        }
    __syncthreads();
    float inv[4];
    #pragma unroll
    for (int r = 0; r < 4; ++r) {
        const int row = (l >> 4) * 4 + r;
        const float z = redz[0][row] + redz[1][row] + redz[2][row] + redz[3][row];
        const float e4 = rede[0][row] + rede[1][row] + rede[2][row] + rede[3][row];
        inv[r] = 1.0f / (e4 + 1e-6f * z);
    }
    #pragma unroll
    for (int st = 0; st < 16; ++st)
        #pragma unroll
        for (int r = 0; r < 4; ++r) {
            const float e = __expf(acc[st][r] - M[r]);
            btT[((size_t)b * NN + m0 + (l >> 4) * 4 + r) * NN + w * 256 + st * 16 + (l & 15)] =
                f2bf(e * mk[st] * inv[r]);
        }
}

// ---------------------------------------------------------------------------
// pv: O[b][c][m] = gamma * (sum_n h[c][n]*btT[m][n]) * mask[m] + x[c][m]
// m97-style 128x128 tile, BK=64, global_load_lds staging.
// ---------------------------------------------------------------------------
__global__ __launch_bounds__(256) void pv_kernel(
    const ushort_t* __restrict__ h, const ushort_t* __restrict__ btT,
    const float* __restrict__ mask, const float* __restrict__ x,
    const float* __restrict__ gamma, float* __restrict__ out)
{
    __shared__ __align__(16) ushort_t sA[128 * 64], sB[128 * 64];
    const int t = threadIdx.x, l = t & 63, w = t >> 6;
    const int b = blockIdx.z, mc0 = blockIdx.x * 128, c0 = blockIdx.y * 128;
    const int wr = w >> 1, wc = w & 1;
    f32x4 acc[4][4] = {};

    for (int kt = 0; kt < 16; ++kt) {
        const int k0 = kt * 64;
        #pragma unroll
        for (int i = 0; i < 4; ++i) {
            const int e = (i * 256 + t) * 8;
            const int row = e >> 6, col = e & 63;
            async_cp16(h + ((size_t)b * CC + c0 + row) * NN + k0 + col,
                       (char*)sA + i * 4096 + t * 16);
            async_cp16(btT + ((size_t)b * NN + mc0 + row) * NN + k0 + col,
                       (char*)sB + i * 4096 + t * 16);
        }
        __syncthreads();
        #pragma unroll
        for (int kc = 0; kc < 2; ++kc) {
            const int fo = kc * 32 + (l >> 4) * 8;
            short8 a[4], bb[4];
            #pragma unroll
            for (int i = 0; i < 4; ++i)
                a[i] = *(const short8*)&sA[(wr * 64 + i * 16 + (l & 15)) * 64 + fo];
            #pragma unroll
            for (int j = 0; j < 4; ++j)
                bb[j] = *(const short8*)&sB[(wc * 64 + j * 16 + (l & 15)) * 64 + fo];
            #pragma unroll
            for (int i = 0; i < 4; ++i)
                #pragma unroll
                for (int j = 0; j < 4; ++j)
                    acc[i][j] = __builtin_amdgcn_mfma_f32_16x16x32_bf16(a[i], bb[j], acc[i][j], 0, 0, 0);
        }
        __syncthreads();
    }

    const float gm = gamma[0];
    #pragma unroll
    for (int j = 0; j < 4; ++j) {
        const int mc = mc0 + wc * 64 + j * 16 + (l & 15);
        const float mv = mask[(size_t)b * NN + mc];
        #pragma unroll
        for (int i = 0; i < 4; ++i) {
            const int cc = c0 + wr * 64 + i * 16 + (l >> 4) * 4;
            #pragma unroll
            for (int r = 0; r < 4; ++r) {
                const size_t o = ((size_t)b * CC + cc + r) * NN + mc;
                out[o] = gm * acc[i][j][r] * mv + x[o];
            }
        }
    }
}

extern "C" void kernel_launch(void* const* d_in, const int* in_sizes, int n_in,
                              void* d_out, int out_size, void* d_ws, size_t ws_size,
                              hipStream_t stream)
{
    const float* x     = (const float*)d_in[0];
    const float* mask  = (const float*)d_in[1];
    const float* Wq    = (const float*)d_in[2];
    const float* Wk    = (const float*)d_in[3];
    const float* Wv    = (const float*)d_in[4];
    const float* gamma = (const float*)d_in[5];
    float* out = (float*)d_out;

    // ws layout (202.1 MB):
    //   [0, 64M):    xthi bf16 [B][N][C]      (later aliased by btT)
    //   [64M,128M):  xtlo bf16 [B][N][C]      (later aliased by btT)
    //   [128M,192M): h    bf16 [B][C][N]
    //   [192M,+):    whi (640x512), wlo (128x512) bf16
    // d_out scratch (first 33.5 MB, dead before pv): fThi|fTlo|gThi|gTlo
    char* ws = (char*)d_ws;
    ushort_t* xthi = (ushort_t*)ws;
    ushort_t* xtlo = (ushort_t*)(ws + 67108864);
    ushort_t* hbuf = (ushort_t*)(ws + 134217728);
    ushort_t* whi  = (ushort_t*)(ws + 201326592);
    ushort_t* wlo  = (ushort_t*)(ws + 201981952);
    ushort_t* btT  = (ushort_t*)ws;              // aliases xthi+xtlo
    ushort_t* fgout = (ushort_t*)d_out;          // scratch planes in d_out

    prep_w<<<dim3(1280), 256, 0, stream>>>(Wq, Wk, Wv, whi, wlo);
    xtrans<<<dim3(16, 8, 64), 256, 0, stream>>>(x, xthi, xtlo);
    fgh_kernel<<<dim3(16, 10, 64), 256, 0, stream>>>(whi, wlo, xthi, xtlo, fgout, hbuf);
    scores_kernel<<<dim3(64, 64), 256, 0, stream>>>(fgout, mask, btT);
    pv_kernel<<<dim3(8, 4, 64), 256, 0, stream>>>(hbuf, btT, mask, x, gamma, out);
}